// Round 16
// baseline (69.642 us; speedup 1.0000x reference)
//
#include <hip/hip_runtime.h>
#include <hip/hip_bf16.h>
#include <stdint.h>

// Problem constants: B=32, T=512, C=F=384, M=2048.
#define B_ 32
#define T_ 512
#define C_ 384
#define F_ 384
#define M_ 2048
#define PT (T_ + 2)      // padded time rows per batch (halo for K=3 conv)
#define KTOT (3 * C_)    // GEMM K = 1152

typedef __bf16 bf16x8 __attribute__((ext_vector_type(8)));
typedef float  f32x4  __attribute__((ext_vector_type(4)));
typedef unsigned short ushort_t;

__device__ __forceinline__ ushort_t f2bf(float f) {
  __hip_bfloat16 h = __float2bfloat16(f);
  return *reinterpret_cast<ushort_t*>(&h);
}
__device__ __forceinline__ uint32_t pack2(float a, float b) {
  return (uint32_t)f2bf(a) | ((uint32_t)f2bf(b) << 16);
}

// ---------------------------------------------------------------------------
// Launch 1: wt transposes | x1p halo zeros | expand (local cumsum; R15).
#define NWB 3456   // = 2*F*KTOT/256
#define NHB 48     // = B*C/256 halo-zero blocks
#define NEXB 4096  // = B * (M/16): 16 pos per block
__global__ __launch_bounds__(256) void prep_expand_kernel(
    const int* __restrict__ target,
    const float* __restrict__ w1, const float* __restrict__ w2,
    const float* __restrict__ enc,     // [B,T,C] f32
    ushort_t* __restrict__ x1p,
    ushort_t* __restrict__ wt1, ushort_t* __restrict__ wt2,
    float* __restrict__ out0,          // [B,M,C]
    float* __restrict__ dec) {         // [B,M]
  const int gid = blockIdx.x;
  const int tid = threadIdx.x;
  if (gid < NWB) {
    // W -> wt_perm (per-(step,wave,fragment,lane) consumption order; R11)
    int idx = gid * 256 + tid;          // 0 .. 2*F*KTOT
    int w = idx >= F_ * KTOT;
    int o = idx - (w ? F_ * KTOT : 0);
    int n = o / KTOT, k = o - n * KTOT;
    int kk = k / C_, c = k - kk * C_;
    int s = kk * 6 + (c >> 6);
    int c64 = c & 63;
    int ks = c64 >> 5, qq = (c64 >> 3) & 3, e = c64 & 7;
    int wv = n / 48, rn = n - wv * 48, fn = rn >> 4, r16 = rn & 15;
    int lane = qq * 16 + r16;
    size_t dst = ((((size_t)s * 8 + wv) * 6 + fn * 2 + ks) << 9) + lane * 8 + e;
    const float* src = w ? w2 : w1;
    (w ? wt2 : wt1)[dst] = f2bf(src[(n * C_ + c) * 3 + kk]);
    return;
  }
  if (gid < NWB + NHB) {
    // x1p halo rows (pr==0 and pr==T+1) zero (gemm1 writes only rows 1..T)
    int idx = (gid - NWB) * 256 + tid;  // 0 .. B*C
    int bb = idx / C_, c = idx - bb * C_;
    x1p[(size_t)(bb * PT) * C_ + c] = 0;
    x1p[(size_t)(bb * PT + T_ + 1) * C_ + c] = 0;
    return;
  }

  // ---------------- expand (16 pos per block, local cumsum) ----------------
  __shared__ int scs[T_];
  const int eb = gid - NWB - NHB;      // 0..4095
  const int b = eb >> 7;               // 128 pos-groups per batch
  const int p0 = (eb & 127) * 16;
  if (tid < 64) {                      // wave 0: inclusive scan of target[b]
    int lane = tid;
    int base = b * T_ + lane * 8;
    int v[8];
#pragma unroll
    for (int i = 0; i < 8; ++i) v[i] = target[base + i];
#pragma unroll
    for (int i = 1; i < 8; ++i) v[i] += v[i - 1];
    int tot = v[7];
    int inc = tot;
#pragma unroll
    for (int d = 1; d < 64; d <<= 1) {
      int t = __shfl_up(inc, d);
      if (lane >= d) inc += t;
    }
    int excl = inc - tot;
#pragma unroll
    for (int i = 0; i < 8; ++i) scs[lane * 8 + i] = v[i] + excl;
  }
  __syncthreads();

  const int lane = tid & 63, wid = tid >> 6;   // 4 waves, 4 pos each
  const int total = scs[T_ - 1];
  const float4 zero = make_float4(0.f, 0.f, 0.f, 0.f);
#pragma unroll
  for (int it = 0; it < 4; ++it) {
    const int pos = p0 + it * 4 + wid;
    const bool valid = pos < total;
    int idx = 0;
#pragma unroll
    for (int step = 512; step; step >>= 1)
      if (idx + step <= T_ && scs[idx + step - 1] <= pos) idx += step;
    int src = idx < T_ ? idx : T_ - 1;
    const float4* srow = (const float4*)(enc + ((size_t)b * T_ + src) * C_);
    float4* orow = (float4*)(out0 + ((size_t)b * M_ + pos) * C_);
    orow[lane] = valid ? srow[lane] : zero;
    if (lane < 32) orow[64 + lane] = valid ? srow[64 + lane] : zero;
    if (lane == 0) dec[b * M_ + pos] = valid ? (float)(pos + 1) : 0.f;
  }
}

// ---------------------------------------------------------------------------
// Launches 2+3: R11's gemm_ln_kernel VERBATIM (the proven-fast 80.9-us parts).
// W streamed L2->reg via wt_perm (coalesced 1KB/inst), X staged once in
// swizzled LDS, barrier-free K-loop, 8 waves, wave owns 48n x 64m.
// Grid = 256 = 1 block/CU, 2 waves/SIMD.
template <bool LAST>
__global__ __launch_bounds__(512, 1) void gemm_ln_kernel(
    const float* __restrict__ enc,     // [B,T,C] f32      (LAST=false)
    const float* __restrict__ mask,    // [B*T]
    const ushort_t* __restrict__ x1p,  // [B][PT][C] bf16  (LAST=true in)
    const ushort_t* __restrict__ wt,   // wt_perm [18][8][6][512] bf16
    const float* __restrict__ bias, const float* __restrict__ g,
    const float* __restrict__ be,
    const float* __restrict__ wl, const float* __restrict__ bl,
    ushort_t* __restrict__ xout,       // [B][PT][C] (LAST=false out)
    float* __restrict__ dpo) {         // [B*T]      (LAST=true out)
  __shared__ char ldsX[66 * 768];      // 49.5 KB X, swizzled
  __shared__ float red[8][64][2];
  __shared__ float stats[64][2];

  const int tid = threadIdx.x;
  const int l = tid & 63, q = l >> 4, r16 = l & 15;
  const int wid = tid >> 6;            // 0..7
  const int b = blockIdx.x >> 3, t0 = (blockIdx.x & 7) * 64;

  // ---- stage X once (reg path, swizzled ds_write) ----
  if (!LAST) {
#pragma unroll
    for (int ps = 0; ps < 7; ++ps) {
      int idx = ps * 512 + tid;        // 16B-chunk index, 66*48 total
      if (idx < 66 * 48) {
        int rl = idx / 48, cp = idx - rl * 48;
        int gc = cp >> 3, ch = cp & 7;
        int t = t0 - 1 + rl;
        uint4 o = make_uint4(0, 0, 0, 0);
        if (t >= 0 && t < T_) {
          const float* src = enc + ((size_t)b * T_ + t) * C_ + gc * 64 + ch * 8;
          float4 u = *(const float4*)src;
          float4 v = *(const float4*)(src + 4);
          float m = mask[b * T_ + t];
          o = make_uint4(pack2(u.x * m, u.y * m), pack2(u.z * m, u.w * m),
                         pack2(v.x * m, v.y * m), pack2(v.z * m, v.w * m));
        }
        *(uint4*)(ldsX + rl * 768 + gc * 128 + ((ch ^ (rl & 7)) << 4)) = o;
      }
    }
  } else {
#pragma unroll
    for (int ps = 0; ps < 7; ++ps) {
      int idx = ps * 512 + tid;
      if (idx < 66 * 48) {
        int rl = idx / 48, cp = idx - rl * 48;
        int gc = cp >> 3, ch = cp & 7;
        uint4 v = *(const uint4*)(x1p + ((size_t)(b * PT + t0 + rl)) * C_ +
                                  gc * 64 + ch * 8);
        *(uint4*)(ldsX + rl * 768 + gc * 128 + ((ch ^ (rl & 7)) << 4)) = v;
      }
    }
  }

  f32x4 acc[3][4];
#pragma unroll
  for (int fn = 0; fn < 3; ++fn)
#pragma unroll
    for (int fm = 0; fm < 4; ++fm) acc[fn][fm] = (f32x4){0.f, 0.f, 0.f, 0.f};

  // W fragment loads for step s: 6 x 1KB coalesced (lane*16B contiguous).
  const ushort_t* wlane = wt + ((size_t)wid * 6 << 9) + (l << 3);
  auto LOADW = [&](bf16x8 (&dst)[3][2], int s) {
    const ushort_t* p = wlane + (((size_t)s * 8 * 6) << 9);
#pragma unroll
    for (int fn = 0; fn < 3; ++fn)
#pragma unroll
      for (int ks = 0; ks < 2; ++ks)
        dst[fn][ks] = *(const bf16x8*)(p + ((fn * 2 + ks) << 9));
  };
  // compute step s: 8 bx ds_reads + 24 MFMA (af from registers)
  auto COMP = [&](bf16x8 (&af)[3][2], int s) {
    const int kk = s / 6, c128 = (s % 6) * 128;
#pragma unroll
    for (int ks = 0; ks < 2; ++ks) {
      bf16x8 bx[4];
#pragma unroll
      for (int fm = 0; fm < 4; ++fm) {
        int rl = fm * 16 + r16 + kk;
        bx[fm] = *(const bf16x8*)(ldsX + rl * 768 + c128 +
                                  (((ks * 4 + q) ^ (rl & 7)) << 4));
      }
#pragma unroll
      for (int fn = 0; fn < 3; ++fn)
#pragma unroll
        for (int fm = 0; fm < 4; ++fm)
          acc[fn][fm] = __builtin_amdgcn_mfma_f32_16x16x32_bf16(
              af[fn][ks], bx[fm], acc[fn][fm], 0, 0, 0);
    }
  };

  bf16x8 afA[3][2], afB[3][2];
  LOADW(afA, 0);
  __syncthreads();  // X staged (the ONLY barrier before the epilogue)
#pragma unroll 1
  for (int s = 0; s < 18; s += 2) {
    LOADW(afB, s + 1);
    COMP(afA, s);
    if (s + 2 < 18) LOADW(afA, s + 2);
    COMP(afB, s + 1);
  }

  // --- epilogue: bias + ReLU ---
#pragma unroll
  for (int fn = 0; fn < 3; ++fn) {
    const int nb = wid * 48 + fn * 16 + q * 4;
    float b0 = bias[nb], b1 = bias[nb + 1], b2 = bias[nb + 2], b3 = bias[nb + 3];
#pragma unroll
    for (int fm = 0; fm < 4; ++fm) {
      acc[fn][fm][0] = fmaxf(acc[fn][fm][0] + b0, 0.f);
      acc[fn][fm][1] = fmaxf(acc[fn][fm][1] + b1, 0.f);
      acc[fn][fm][2] = fmaxf(acc[fn][fm][2] + b2, 0.f);
      acc[fn][fm][3] = fmaxf(acc[fn][fm][3] + b3, 0.f);
    }
  }

  // --- LN stats ---
#pragma unroll
  for (int fm = 0; fm < 4; ++fm) {
    float s = 0.f, s2 = 0.f;
#pragma unroll
    for (int fn = 0; fn < 3; ++fn)
#pragma unroll
      for (int j = 0; j < 4; ++j) {
        float v = acc[fn][fm][j];
        s += v; s2 += v * v;
      }
    s += __shfl_xor(s, 16); s += __shfl_xor(s, 32);
    s2 += __shfl_xor(s2, 16); s2 += __shfl_xor(s2, 32);
    if (l < 16) { red[wid][fm * 16 + r16][0] = s; red[wid][fm * 16 + r16][1] = s2; }
  }
  __syncthreads();
  if (tid < 64) {
    float S = 0.f, S2 = 0.f;
#pragma unroll
    for (int w = 0; w < 8; ++w) { S += red[w][tid][0]; S2 += red[w][tid][1]; }
    float mu = S / F_;
    stats[tid][0] = mu;
    stats[tid][1] = rsqrtf(S2 / F_ - mu * mu + 1e-5f);
  }
  __syncthreads();

  if (!LAST) {
#pragma unroll
    for (int fn = 0; fn < 3; ++fn) {
      const int nb = wid * 48 + fn * 16 + q * 4;
      float g0 = g[nb], g1 = g[nb + 1], g2 = g[nb + 2], g3 = g[nb + 3];
      float e0 = be[nb], e1 = be[nb + 1], e2 = be[nb + 2], e3 = be[nb + 3];
#pragma unroll
      for (int fm = 0; fm < 4; ++fm) {
        const int m = fm * 16 + r16;
        const float mu = stats[m][0], rs = stats[m][1];
        uint32_t p0 = pack2((acc[fn][fm][0] - mu) * rs * g0 + e0,
                            (acc[fn][fm][1] - mu) * rs * g1 + e1);
        uint32_t p1 = pack2((acc[fn][fm][2] - mu) * rs * g2 + e2,
                            (acc[fn][fm][3] - mu) * rs * g3 + e3);
        *(uint2*)(xout + ((size_t)(b * PT + 1 + t0 + m)) * C_ + nb) =
            make_uint2(p0, p1);
      }
    }
  } else {
    float p[4] = {0.f, 0.f, 0.f, 0.f};
#pragma unroll
    for (int fn = 0; fn < 3; ++fn) {
      const int nb = wid * 48 + fn * 16 + q * 4;
      float g0 = g[nb], g1 = g[nb + 1], g2 = g[nb + 2], g3 = g[nb + 3];
      float e0 = be[nb], e1 = be[nb + 1], e2 = be[nb + 2], e3 = be[nb + 3];
      float l0 = wl[nb], l1 = wl[nb + 1], l2 = wl[nb + 2], l3 = wl[nb + 3];
#pragma unroll
      for (int fm = 0; fm < 4; ++fm) {
        const int m = fm * 16 + r16;
        const float mu = stats[m][0], rs = stats[m][1];
        p[fm] += ((acc[fn][fm][0] - mu) * rs * g0 + e0) * l0 +
                 ((acc[fn][fm][1] - mu) * rs * g1 + e1) * l1 +
                 ((acc[fn][fm][2] - mu) * rs * g2 + e2) * l2 +
                 ((acc[fn][fm][3] - mu) * rs * g3 + e3) * l3;
      }
    }
    __syncthreads();  // red reuse
#pragma unroll
    for (int fm = 0; fm < 4; ++fm) {
      float s = p[fm];
      s += __shfl_xor(s, 16); s += __shfl_xor(s, 32);
      if (l < 16) red[wid][fm * 16 + r16][0] = s;
    }
    __syncthreads();
    if (tid < 64) {
      float S = 0.f;
#pragma unroll
      for (int w = 0; w < 8; ++w) S += red[w][tid][0];
      int t = t0 + tid;
      dpo[b * T_ + t] = (S + bl[0]) * mask[b * T_ + t];
    }
  }
}

// ---------------------------------------------------------------------------
extern "C" void kernel_launch(void* const* d_in, const int* in_sizes, int n_in,
                              void* d_out, int out_size, void* d_ws,
                              size_t ws_size, hipStream_t stream) {
  const float* enc    = (const float*)d_in[0];
  const float* mask   = (const float*)d_in[1];
  const int*   target = (const int*)d_in[2];
  const float* w1    = (const float*)d_in[4];
  const float* b1    = (const float*)d_in[5];
  const float* g1    = (const float*)d_in[6];
  const float* beta1 = (const float*)d_in[7];
  const float* w2    = (const float*)d_in[8];
  const float* b2    = (const float*)d_in[9];
  const float* g2    = (const float*)d_in[10];
  const float* beta2 = (const float*)d_in[11];
  const float* wl    = (const float*)d_in[12];
  const float* bl    = (const float*)d_in[13];

  // Workspace (bf16): x1p (padded) | wt1 | wt2 (permuted)
  ushort_t* x1p = (ushort_t*)d_ws;                    // [B][PT][C]
  ushort_t* wt1 = x1p + (size_t)B_ * PT * C_;         // [18][8][6][512]
  ushort_t* wt2 = wt1 + (size_t)F_ * KTOT;

  float* out0 = (float*)d_out;                        // [B,M,C]
  float* dec  = out0 + (size_t)B_ * M_ * C_;          // [B,M]
  float* dpo  = dec + (size_t)B_ * M_;                // [B,T]

  prep_expand_kernel<<<NWB + NHB + NEXB, 256, 0, stream>>>(
      target, w1, w2, enc, x1p, wt1, wt2, out0, dec);

  gemm_ln_kernel<false><<<B_ * (T_ / 64), 512, 0, stream>>>(
      enc, mask, nullptr, wt1, b1, g1, beta1, nullptr, nullptr, x1p, nullptr);
  gemm_ln_kernel<true><<<B_ * (T_ / 64), 512, 0, stream>>>(
      nullptr, mask, x1p, wt2, b2, g2, beta2, wl, bl, nullptr, dpo);
}

// Round 17
// 65.592 us; speedup vs baseline: 1.0618x; 1.0618x over previous
//
#include <hip/hip_runtime.h>
#include <hip/hip_bf16.h>
#include <stdint.h>

// Problem constants: B=32, T=512, C=F=384, M=2048.
#define B_ 32
#define T_ 512
#define C_ 384
#define F_ 384
#define M_ 2048
#define KTOT (3 * C_)    // GEMM K = 1152

typedef __bf16 bf16x8 __attribute__((ext_vector_type(8)));
typedef float  f32x4  __attribute__((ext_vector_type(4)));
typedef unsigned short ushort_t;

__device__ __forceinline__ ushort_t f2bf(float f) {
  __hip_bfloat16 h = __float2bfloat16(f);
  return *reinterpret_cast<ushort_t*>(&h);
}
__device__ __forceinline__ uint32_t pack2(float a, float b) {
  return (uint32_t)f2bf(a) | ((uint32_t)f2bf(b) << 16);
}

// ---------------------------------------------------------------------------
// Launch 1: wt transposes (blocks 0..NWB-1) + expand (local cumsum; R15).
#define NWB 3456   // = 2*F*KTOT/256
#define NEXB 4096  // = B * (M/16): 16 pos per block
__global__ __launch_bounds__(256) void prep_expand_kernel(
    const int* __restrict__ target,
    const float* __restrict__ w1, const float* __restrict__ w2,
    const float* __restrict__ enc,     // [B,T,C] f32
    ushort_t* __restrict__ wt1, ushort_t* __restrict__ wt2,
    float* __restrict__ out0,          // [B,M,C]
    float* __restrict__ dec) {         // [B,M]
  const int gid = blockIdx.x;
  const int tid = threadIdx.x;
  if (gid < NWB) {
    // W -> wt_perm (per-(step,wave,fragment,lane) consumption order; R11)
    int idx = gid * 256 + tid;          // 0 .. 2*F*KTOT
    int w = idx >= F_ * KTOT;
    int o = idx - (w ? F_ * KTOT : 0);
    int n = o / KTOT, k = o - n * KTOT;
    int kk = k / C_, c = k - kk * C_;
    int s = kk * 6 + (c >> 6);
    int c64 = c & 63;
    int ks = c64 >> 5, qq = (c64 >> 3) & 3, e = c64 & 7;
    int wv = n / 48, rn = n - wv * 48, fn = rn >> 4, r16 = rn & 15;
    int lane = qq * 16 + r16;
    size_t dst = ((((size_t)s * 8 + wv) * 6 + fn * 2 + ks) << 9) + lane * 8 + e;
    const float* src = w ? w2 : w1;
    (w ? wt2 : wt1)[dst] = f2bf(src[(n * C_ + c) * 3 + kk]);
    return;
  }

  // ---------------- expand (16 pos per block, local cumsum) ----------------
  __shared__ int scs[T_];
  const int eb = gid - NWB;            // 0..4095
  const int b = eb >> 7;               // 128 pos-groups per batch
  const int p0 = (eb & 127) * 16;
  if (tid < 64) {                      // wave 0: inclusive scan of target[b]
    int lane = tid;
    int base = b * T_ + lane * 8;
    int v[8];
#pragma unroll
    for (int i = 0; i < 8; ++i) v[i] = target[base + i];
#pragma unroll
    for (int i = 1; i < 8; ++i) v[i] += v[i - 1];
    int tot = v[7];
    int inc = tot;
#pragma unroll
    for (int d = 1; d < 64; d <<= 1) {
      int t = __shfl_up(inc, d);
      if (lane >= d) inc += t;
    }
    int excl = inc - tot;
#pragma unroll
    for (int i = 0; i < 8; ++i) scs[lane * 8 + i] = v[i] + excl;
  }
  __syncthreads();

  const int lane = tid & 63, wid = tid >> 6;   // 4 waves, 4 pos each
  const int total = scs[T_ - 1];
  const float4 zero = make_float4(0.f, 0.f, 0.f, 0.f);
#pragma unroll
  for (int it = 0; it < 4; ++it) {
    const int pos = p0 + it * 4 + wid;
    const bool valid = pos < total;
    int idx = 0;
#pragma unroll
    for (int step = 512; step; step >>= 1)
      if (idx + step <= T_ && scs[idx + step - 1] <= pos) idx += step;
    int src = idx < T_ ? idx : T_ - 1;
    const float4* srow = (const float4*)(enc + ((size_t)b * T_ + src) * C_);
    float4* orow = (float4*)(out0 + ((size_t)b * M_ + pos) * C_);
    orow[lane] = valid ? srow[lane] : zero;
    if (lane < 32) orow[64 + lane] = valid ? srow[64 + lane] : zero;
    if (lane == 0) dec[b * M_ + pos] = valid ? (float)(pos + 1) : 0.f;
  }
}

// ---------------------------------------------------------------------------
// Launch 2: fused conv1+LN1+conv2+LN2+linear (R15 structure, race-fixed),
// with BOTH operand streams software-pipelined one step ahead: LOADW (L2->reg,
// R11) and NEW: LOADBX (LDS->reg) -- the lgkm waits drain under the previous
// step's MFMA block instead of stalling cold (R14 counters: MfmaUtil 15%,
// ~65% stall -> ds_read latency was on the critical path each step).
// 8 waves, wave owns 48n. Grid = 256 = 1 block/CU, 2 waves/SIMD (bounds cap
// VGPR at 256 so the 8-wave block stays resident).
__global__ __launch_bounds__(512, 2) void gemm12_kernel(
    const float* __restrict__ enc,     // [B,T,C] f32
    const float* __restrict__ mask,    // [B*T]
    const ushort_t* __restrict__ wt1,  // wt_perm [18][8][6][512] bf16
    const ushort_t* __restrict__ wt2,
    const float* __restrict__ b1, const float* __restrict__ g1,
    const float* __restrict__ be1,
    const float* __restrict__ b2, const float* __restrict__ g2,
    const float* __restrict__ be2,
    const float* __restrict__ wl, const float* __restrict__ bl,
    float* __restrict__ dpo) {         // [B*T]
  __shared__ char ldsX[82 * 768];      // 61.5 KB: X0 rows enc[t0-2..t0+79]
  __shared__ float red[8][80][2];
  __shared__ float stats[80][2];

  const int tid = threadIdx.x;
  const int l = tid & 63, q = l >> 4, r16 = l & 15;
  const int wid = tid >> 6;            // 0..7
  const int b = blockIdx.x >> 3, t0 = (blockIdx.x & 7) * 64;

  // ---- stage X0: 82 rows (enc f32 * mask -> bf16, swizzled) ----
#pragma unroll
  for (int ps = 0; ps < 8; ++ps) {
    int idx = ps * 512 + tid;          // 16B-chunk index, 82*48 = 3936 total
    if (idx < 82 * 48) {
      int rl = idx / 48, cp = idx - rl * 48;
      int gc = cp >> 3, ch = cp & 7;
      int t = t0 - 2 + rl;
      uint4 o = make_uint4(0, 0, 0, 0);
      if (t >= 0 && t < T_) {
        const float* src = enc + ((size_t)b * T_ + t) * C_ + gc * 64 + ch * 8;
        float4 u = *(const float4*)src;
        float4 v = *(const float4*)(src + 4);
        float m = mask[b * T_ + t];
        o = make_uint4(pack2(u.x * m, u.y * m), pack2(u.z * m, u.w * m),
                       pack2(v.x * m, v.y * m), pack2(v.z * m, v.w * m));
      }
      *(uint4*)(ldsX + rl * 768 + gc * 128 + ((ch ^ (rl & 7)) << 4)) = o;
    }
  }

  const ushort_t* wlane1 = wt1 + ((size_t)wid * 6 << 9) + (l << 3);
  const ushort_t* wlane2 = wt2 + ((size_t)wid * 6 << 9) + (l << 3);
  auto LOADW = [&](const ushort_t* wlane, bf16x8 (&dst)[3][2], int s) {
    const ushort_t* p = wlane + (((size_t)s * 48) << 9);
#pragma unroll
    for (int fn = 0; fn < 3; ++fn)
#pragma unroll
      for (int ks = 0; ks < 2; ++ks)
        dst[fn][ks] = *(const bf16x8*)(p + ((fn * 2 + ks) << 9));
  };

  // ================= GEMM1: 5 m-frags (rows m' = 0..79, valid 0..65) =======
  f32x4 acc1[3][5];
#pragma unroll
  for (int fn = 0; fn < 3; ++fn)
#pragma unroll
    for (int fm = 0; fm < 5; ++fm) acc1[fn][fm] = (f32x4){0.f, 0.f, 0.f, 0.f};

  auto LOADBX1 = [&](bf16x8 (&dst)[5][2], int s) {
    const int kk = s / 6, c128 = (s % 6) * 128;
#pragma unroll
    for (int fm = 0; fm < 5; ++fm) {
      int rl = fm * 16 + r16 + kk;
#pragma unroll
      for (int ks = 0; ks < 2; ++ks)
        dst[fm][ks] = *(const bf16x8*)(ldsX + rl * 768 + c128 +
                                       (((ks * 4 + q) ^ (rl & 7)) << 4));
    }
  };
  auto MFMA1 = [&](bf16x8 (&af)[3][2], bf16x8 (&bx)[5][2]) {
#pragma unroll
    for (int ks = 0; ks < 2; ++ks)
#pragma unroll
      for (int fn = 0; fn < 3; ++fn)
#pragma unroll
        for (int fm = 0; fm < 5; ++fm)
          acc1[fn][fm] = __builtin_amdgcn_mfma_f32_16x16x32_bf16(
              af[fn][ks], bx[fm][ks], acc1[fn][fm], 0, 0, 0);
  };

  {
    bf16x8 afA[3][2], afB[3][2];
    bf16x8 bxA[5][2], bxB[5][2];
    LOADW(wlane1, afA, 0);
    __syncthreads();  // X0 staged
    LOADBX1(bxA, 0);
#pragma unroll 1
    for (int s = 0; s < 18; s += 2) {
      LOADW(wlane1, afB, s + 1);
      LOADBX1(bxB, s + 1);
      MFMA1(afA, bxA);               // step s: operands fully in registers
      if (s + 2 < 18) {
        LOADW(wlane1, afA, s + 2);
        LOADBX1(bxA, s + 2);
      }
      MFMA1(afB, bxB);               // step s+1
    }
  }

  // ---- epilogue1: bias+ReLU, LN stats (rows 0..65 meaningful) ----
#pragma unroll
  for (int fn = 0; fn < 3; ++fn) {
    const int nb = wid * 48 + fn * 16 + q * 4;
    float c0 = b1[nb], c1 = b1[nb + 1], c2 = b1[nb + 2], c3 = b1[nb + 3];
#pragma unroll
    for (int fm = 0; fm < 5; ++fm) {
      acc1[fn][fm][0] = fmaxf(acc1[fn][fm][0] + c0, 0.f);
      acc1[fn][fm][1] = fmaxf(acc1[fn][fm][1] + c1, 0.f);
      acc1[fn][fm][2] = fmaxf(acc1[fn][fm][2] + c2, 0.f);
      acc1[fn][fm][3] = fmaxf(acc1[fn][fm][3] + c3, 0.f);
    }
  }
#pragma unroll
  for (int fm = 0; fm < 5; ++fm) {
    float s = 0.f, s2 = 0.f;
#pragma unroll
    for (int fn = 0; fn < 3; ++fn)
#pragma unroll
      for (int j = 0; j < 4; ++j) {
        float v = acc1[fn][fm][j];
        s += v; s2 += v * v;
      }
    s += __shfl_xor(s, 16); s += __shfl_xor(s, 32);
    s2 += __shfl_xor(s2, 16); s2 += __shfl_xor(s2, 32);
    if (l < 16) { red[wid][fm * 16 + r16][0] = s; red[wid][fm * 16 + r16][1] = s2; }
  }
  __syncthreads();   // also guarantees all waves done reading X0
  if (tid < 66) {
    float S = 0.f, S2 = 0.f;
#pragma unroll
    for (int w = 0; w < 8; ++w) { S += red[w][tid][0]; S2 += red[w][tid][1]; }
    float mu = S / F_;
    stats[tid][0] = mu;
    stats[tid][1] = rsqrtf(S2 / F_ - mu * mu + 1e-5f);
  }
  __syncthreads();

  // ---- LN1 -> ldsX (swizzled bf16). Edge rows excluded (zeroed below). ----
  const int mlo = (t0 == 0) ? 1 : 0;
  const int mhi = (t0 == T_ - 64) ? 65 : 66;
#pragma unroll
  for (int fn = 0; fn < 3; ++fn) {
    const int nb = wid * 48 + fn * 16 + q * 4;
    float g0 = g1[nb], gg1 = g1[nb + 1], g2v = g1[nb + 2], g3 = g1[nb + 3];
    float e0 = be1[nb], e1 = be1[nb + 1], e2 = be1[nb + 2], e3 = be1[nb + 3];
#pragma unroll
    for (int fm = 0; fm < 5; ++fm) {
      const int m = fm * 16 + r16;
      if (m >= mlo && m < mhi) {
        const float mu = stats[m][0], rs = stats[m][1];
        uint32_t p0 = pack2((acc1[fn][fm][0] - mu) * rs * g0 + e0,
                            (acc1[fn][fm][1] - mu) * rs * gg1 + e1);
        uint32_t p1 = pack2((acc1[fn][fm][2] - mu) * rs * g2v + e2,
                            (acc1[fn][fm][3] - mu) * rs * g3 + e3);
        *(uint2*)(ldsX + m * 768 + (((nb >> 3) ^ (m & 7)) << 4) +
                  ((q & 1) << 3)) = make_uint2(p0, p1);
      }
    }
  }
  // conv2's zero padding at sequence edges (sole writer of these rows)
  if (t0 == 0 && tid < 48)
    *(uint4*)(ldsX + tid * 16) = make_uint4(0, 0, 0, 0);
  if (t0 == T_ - 64 && tid < 48)
    *(uint4*)(ldsX + 65 * 768 + tid * 16) = make_uint4(0, 0, 0, 0);

  // ================= GEMM2: 4 m-frags (reads ldsX rows 0..65) ==============
  f32x4 acc2[3][4];
#pragma unroll
  for (int fn = 0; fn < 3; ++fn)
#pragma unroll
    for (int fm = 0; fm < 4; ++fm) acc2[fn][fm] = (f32x4){0.f, 0.f, 0.f, 0.f};

  auto LOADBX2 = [&](bf16x8 (&dst)[4][2], int s) {
    const int kk = s / 6, c128 = (s % 6) * 128;
#pragma unroll
    for (int fm = 0; fm < 4; ++fm) {
      int rl = fm * 16 + r16 + kk;
#pragma unroll
      for (int ks = 0; ks < 2; ++ks)
        dst[fm][ks] = *(const bf16x8*)(ldsX + rl * 768 + c128 +
                                       (((ks * 4 + q) ^ (rl & 7)) << 4));
    }
  };
  auto MFMA2 = [&](bf16x8 (&af)[3][2], bf16x8 (&bx)[4][2]) {
#pragma unroll
    for (int ks = 0; ks < 2; ++ks)
#pragma unroll
      for (int fn = 0; fn < 3; ++fn)
#pragma unroll
        for (int fm = 0; fm < 4; ++fm)
          acc2[fn][fm] = __builtin_amdgcn_mfma_f32_16x16x32_bf16(
              af[fn][ks], bx[fm][ks], acc2[fn][fm], 0, 0, 0);
  };

  {
    bf16x8 afA[3][2], afB[3][2];
    bf16x8 bxA[4][2], bxB[4][2];
    LOADW(wlane2, afA, 0);   // issued before the barrier: hides L2 latency
    __syncthreads();         // LN1 writes + pad zeros visible
    LOADBX2(bxA, 0);
#pragma unroll 1
    for (int s = 0; s < 18; s += 2) {
      LOADW(wlane2, afB, s + 1);
      LOADBX2(bxB, s + 1);
      MFMA2(afA, bxA);
      if (s + 2 < 18) {
        LOADW(wlane2, afA, s + 2);
        LOADBX2(bxA, s + 2);
      }
      MFMA2(afB, bxB);
    }
  }

  // ---- epilogue2: bias+ReLU, LN, fused linear + mask -> dpo ----
#pragma unroll
  for (int fn = 0; fn < 3; ++fn) {
    const int nb = wid * 48 + fn * 16 + q * 4;
    float c0 = b2[nb], c1 = b2[nb + 1], c2 = b2[nb + 2], c3 = b2[nb + 3];
#pragma unroll
    for (int fm = 0; fm < 4; ++fm) {
      acc2[fn][fm][0] = fmaxf(acc2[fn][fm][0] + c0, 0.f);
      acc2[fn][fm][1] = fmaxf(acc2[fn][fm][1] + c1, 0.f);
      acc2[fn][fm][2] = fmaxf(acc2[fn][fm][2] + c2, 0.f);
      acc2[fn][fm][3] = fmaxf(acc2[fn][fm][3] + c3, 0.f);
    }
  }
  __syncthreads();  // red/stats reuse
#pragma unroll
  for (int fm = 0; fm < 4; ++fm) {
    float s = 0.f, s2 = 0.f;
#pragma unroll
    for (int fn = 0; fn < 3; ++fn)
#pragma unroll
      for (int j = 0; j < 4; ++j) {
        float v = acc2[fn][fm][j];
        s += v; s2 += v * v;
      }
    s += __shfl_xor(s, 16); s += __shfl_xor(s, 32);
    s2 += __shfl_xor(s2, 16); s2 += __shfl_xor(s2, 32);
    if (l < 16) { red[wid][fm * 16 + r16][0] = s; red[wid][fm * 16 + r16][1] = s2; }
  }
  __syncthreads();
  if (tid < 64) {
    float S = 0.f, S2 = 0.f;
#pragma unroll
    for (int w = 0; w < 8; ++w) { S += red[w][tid][0]; S2 += red[w][tid][1]; }
    float mu = S / F_;
    stats[tid][0] = mu;
    stats[tid][1] = rsqrtf(S2 / F_ - mu * mu + 1e-5f);
  }
  __syncthreads();

  float p[4] = {0.f, 0.f, 0.f, 0.f};
#pragma unroll
  for (int fn = 0; fn < 3; ++fn) {
    const int nb = wid * 48 + fn * 16 + q * 4;
    float g0 = g2[nb], gg1 = g2[nb + 1], g2v = g2[nb + 2], g3 = g2[nb + 3];
    float e0 = be2[nb], e1 = be2[nb + 1], e2 = be2[nb + 2], e3 = be2[nb + 3];
    float l0 = wl[nb], l1 = wl[nb + 1], l2 = wl[nb + 2], l3 = wl[nb + 3];
#pragma unroll
    for (int fm = 0; fm < 4; ++fm) {
      const int m = fm * 16 + r16;
      const float mu = stats[m][0], rs = stats[m][1];
      p[fm] += ((acc2[fn][fm][0] - mu) * rs * g0 + e0) * l0 +
               ((acc2[fn][fm][1] - mu) * rs * gg1 + e1) * l1 +
               ((acc2[fn][fm][2] - mu) * rs * g2v + e2) * l2 +
               ((acc2[fn][fm][3] - mu) * rs * g3 + e3) * l3;
    }
  }
  __syncthreads();  // red reuse
#pragma unroll
  for (int fm = 0; fm < 4; ++fm) {
    float s = p[fm];
    s += __shfl_xor(s, 16); s += __shfl_xor(s, 32);
    if (l < 16) red[wid][fm * 16 + r16][0] = s;
  }
  __syncthreads();
  if (tid < 64) {
    float S = 0.f;
#pragma unroll
    for (int w = 0; w < 8; ++w) S += red[w][tid][0];
    int t = t0 + tid;
    dpo[b * T_ + t] = (S + bl[0]) * mask[b * T_ + t];
  }
}

// ---------------------------------------------------------------------------
extern "C" void kernel_launch(void* const* d_in, const int* in_sizes, int n_in,
                              void* d_out, int out_size, void* d_ws,
                              size_t ws_size, hipStream_t stream) {
  const float* enc    = (const float*)d_in[0];
  const float* mask   = (const float*)d_in[1];
  const int*   target = (const int*)d_in[2];
  const float* w1    = (const float*)d_in[4];
  const float* b1    = (const float*)d_in[5];
  const float* g1    = (const float*)d_in[6];
  const float* beta1 = (const float*)d_in[7];
  const float* w2    = (const float*)d_in[8];
  const float* b2    = (const float*)d_in[9];
  const float* g2    = (const float*)d_in[10];
  const float* beta2 = (const float*)d_in[11];
  const float* wl    = (const float*)d_in[12];
  const float* bl    = (const float*)d_in[13];

  // Workspace (bf16): wt1 | wt2 (permuted)
  ushort_t* wt1 = (ushort_t*)d_ws;                    // [18][8][6][512]
  ushort_t* wt2 = wt1 + (size_t)F_ * KTOT;

  float* out0 = (float*)d_out;                        // [B,M,C]
  float* dec  = out0 + (size_t)B_ * M_ * C_;          // [B,M]
  float* dpo  = dec + (size_t)B_ * M_;                // [B,T]

  prep_expand_kernel<<<NWB + NEXB, 256, 0, stream>>>(
      target, w1, w2, enc, wt1, wt2, out0, dec);

  gemm12_kernel<<<256, 512, 0, stream>>>(
      enc, mask, wt1, wt2, b1, g1, beta1, b2, g2, beta2, wl, bl, dpo);
}

// Round 18
// 65.208 us; speedup vs baseline: 1.0680x; 1.0059x over previous
//
#include <hip/hip_runtime.h>
#include <hip/hip_bf16.h>
#include <stdint.h>

// Problem constants: B=32, T=512, C=F=384, M=2048.
#define B_ 32
#define T_ 512
#define C_ 384
#define F_ 384
#define M_ 2048
#define KTOT (3 * C_)    // GEMM K = 1152

typedef __bf16 bf16x8 __attribute__((ext_vector_type(8)));
typedef float  f32x4  __attribute__((ext_vector_type(4)));
typedef unsigned short ushort_t;

__device__ __forceinline__ ushort_t f2bf(float f) {
  __hip_bfloat16 h = __float2bfloat16(f);
  return *reinterpret_cast<ushort_t*>(&h);
}
__device__ __forceinline__ uint32_t pack2(float a, float b) {
  return (uint32_t)f2bf(a) | ((uint32_t)f2bf(b) << 16);
}

// ---------------------------------------------------------------------------
// Launch 1: wt transposes (blocks 0..NWB-1) + expand (local cumsum; R15).
#define NWB 3456   // = 2*F*KTOT/256
#define NEXB 4096  // = B * (M/16): 16 pos per block
__global__ __launch_bounds__(256) void prep_expand_kernel(
    const int* __restrict__ target,
    const float* __restrict__ w1, const float* __restrict__ w2,
    const float* __restrict__ enc,     // [B,T,C] f32
    ushort_t* __restrict__ wt1, ushort_t* __restrict__ wt2,
    float* __restrict__ out0,          // [B,M,C]
    float* __restrict__ dec) {         // [B,M]
  const int gid = blockIdx.x;
  const int tid = threadIdx.x;
  if (gid < NWB) {
    // W -> wt_perm (per-(step,wave,fragment,lane) consumption order; R11)
    int idx = gid * 256 + tid;          // 0 .. 2*F*KTOT
    int w = idx >= F_ * KTOT;
    int o = idx - (w ? F_ * KTOT : 0);
    int n = o / KTOT, k = o - n * KTOT;
    int kk = k / C_, c = k - kk * C_;
    int s = kk * 6 + (c >> 6);
    int c64 = c & 63;
    int ks = c64 >> 5, qq = (c64 >> 3) & 3, e = c64 & 7;
    int wv = n / 48, rn = n - wv * 48, fn = rn >> 4, r16 = rn & 15;
    int lane = qq * 16 + r16;
    size_t dst = ((((size_t)s * 8 + wv) * 6 + fn * 2 + ks) << 9) + lane * 8 + e;
    const float* src = w ? w2 : w1;
    (w ? wt2 : wt1)[dst] = f2bf(src[(n * C_ + c) * 3 + kk]);
    return;
  }

  // ---------------- expand (16 pos per block, local cumsum) ----------------
  __shared__ int scs[T_];
  const int eb = gid - NWB;            // 0..4095
  const int b = eb >> 7;               // 128 pos-groups per batch
  const int p0 = (eb & 127) * 16;
  if (tid < 64) {                      // wave 0: inclusive scan of target[b]
    int lane = tid;
    int base = b * T_ + lane * 8;
    int v[8];
#pragma unroll
    for (int i = 0; i < 8; ++i) v[i] = target[base + i];
#pragma unroll
    for (int i = 1; i < 8; ++i) v[i] += v[i - 1];
    int tot = v[7];
    int inc = tot;
#pragma unroll
    for (int d = 1; d < 64; d <<= 1) {
      int t = __shfl_up(inc, d);
      if (lane >= d) inc += t;
    }
    int excl = inc - tot;
#pragma unroll
    for (int i = 0; i < 8; ++i) scs[lane * 8 + i] = v[i] + excl;
  }
  __syncthreads();

  const int lane = tid & 63, wid = tid >> 6;   // 4 waves, 4 pos each
  const int total = scs[T_ - 1];
  const float4 zero = make_float4(0.f, 0.f, 0.f, 0.f);
#pragma unroll
  for (int it = 0; it < 4; ++it) {
    const int pos = p0 + it * 4 + wid;
    const bool valid = pos < total;
    int idx = 0;
#pragma unroll
    for (int step = 512; step; step >>= 1)
      if (idx + step <= T_ && scs[idx + step - 1] <= pos) idx += step;
    int src = idx < T_ ? idx : T_ - 1;
    const float4* srow = (const float4*)(enc + ((size_t)b * T_ + src) * C_);
    float4* orow = (float4*)(out0 + ((size_t)b * M_ + pos) * C_);
    orow[lane] = valid ? srow[lane] : zero;
    if (lane < 32) orow[64 + lane] = valid ? srow[64 + lane] : zero;
    if (lane == 0) dec[b * M_ + pos] = valid ? (float)(pos + 1) : 0.f;
  }
}

// ---------------------------------------------------------------------------
// Launch 2: fused conv1+LN1+conv2+LN2+linear (R15 structure, race-fixed),
// with the W (L2) stream software-pipelined TWO steps ahead via a 3-set af
// rotation: prefetch distance = 2 MFMA phases (~300-580 cyc) covers loaded-L2
// latency, which one phase (~150-300 cyc at 2 waves/SIMD) could not.
// bx reads stay inline in COMP (R17 showed LDS prefetch is null).
// 8 waves, wave owns 48n. Grid = 256 = 1 block/CU, 2 waves/SIMD.
__global__ __launch_bounds__(512, 2) void gemm12_kernel(
    const float* __restrict__ enc,     // [B,T,C] f32
    const float* __restrict__ mask,    // [B*T]
    const ushort_t* __restrict__ wt1,  // wt_perm [18][8][6][512] bf16
    const ushort_t* __restrict__ wt2,
    const float* __restrict__ b1, const float* __restrict__ g1,
    const float* __restrict__ be1,
    const float* __restrict__ b2, const float* __restrict__ g2,
    const float* __restrict__ be2,
    const float* __restrict__ wl, const float* __restrict__ bl,
    float* __restrict__ dpo) {         // [B*T]
  __shared__ char ldsX[82 * 768];      // 61.5 KB: X0 rows enc[t0-2..t0+79]
  __shared__ float red[8][80][2];
  __shared__ float stats[80][2];

  const int tid = threadIdx.x;
  const int l = tid & 63, q = l >> 4, r16 = l & 15;
  const int wid = tid >> 6;            // 0..7
  const int b = blockIdx.x >> 3, t0 = (blockIdx.x & 7) * 64;

  // ---- stage X0: 82 rows (enc f32 * mask -> bf16, swizzled) ----
#pragma unroll
  for (int ps = 0; ps < 8; ++ps) {
    int idx = ps * 512 + tid;          // 16B-chunk index, 82*48 = 3936 total
    if (idx < 82 * 48) {
      int rl = idx / 48, cp = idx - rl * 48;
      int gc = cp >> 3, ch = cp & 7;
      int t = t0 - 2 + rl;
      uint4 o = make_uint4(0, 0, 0, 0);
      if (t >= 0 && t < T_) {
        const float* src = enc + ((size_t)b * T_ + t) * C_ + gc * 64 + ch * 8;
        float4 u = *(const float4*)src;
        float4 v = *(const float4*)(src + 4);
        float m = mask[b * T_ + t];
        o = make_uint4(pack2(u.x * m, u.y * m), pack2(u.z * m, u.w * m),
                       pack2(v.x * m, v.y * m), pack2(v.z * m, v.w * m));
      }
      *(uint4*)(ldsX + rl * 768 + gc * 128 + ((ch ^ (rl & 7)) << 4)) = o;
    }
  }

  const ushort_t* wlane1 = wt1 + ((size_t)wid * 6 << 9) + (l << 3);
  const ushort_t* wlane2 = wt2 + ((size_t)wid * 6 << 9) + (l << 3);
  auto LOADW = [&](const ushort_t* wlane, bf16x8 (&dst)[3][2], int s) {
    const ushort_t* p = wlane + (((size_t)s * 48) << 9);
#pragma unroll
    for (int fn = 0; fn < 3; ++fn)
#pragma unroll
      for (int ks = 0; ks < 2; ++ks)
        dst[fn][ks] = *(const bf16x8*)(p + ((fn * 2 + ks) << 9));
  };

  // ================= GEMM1: 5 m-frags (rows m' = 0..79, valid 0..65) =======
  f32x4 acc1[3][5];
#pragma unroll
  for (int fn = 0; fn < 3; ++fn)
#pragma unroll
    for (int fm = 0; fm < 5; ++fm) acc1[fn][fm] = (f32x4){0.f, 0.f, 0.f, 0.f};

  auto COMP1 = [&](bf16x8 (&af)[3][2], int s) {
    const int kk = s / 6, c128 = (s % 6) * 128;
#pragma unroll
    for (int ks = 0; ks < 2; ++ks) {
      bf16x8 bx[5];
#pragma unroll
      for (int fm = 0; fm < 5; ++fm) {
        int rl = fm * 16 + r16 + kk;
        bx[fm] = *(const bf16x8*)(ldsX + rl * 768 + c128 +
                                  (((ks * 4 + q) ^ (rl & 7)) << 4));
      }
#pragma unroll
      for (int fn = 0; fn < 3; ++fn)
#pragma unroll
        for (int fm = 0; fm < 5; ++fm)
          acc1[fn][fm] = __builtin_amdgcn_mfma_f32_16x16x32_bf16(
              af[fn][ks], bx[fm], acc1[fn][fm], 0, 0, 0);
    }
  };

  {
    bf16x8 af0[3][2], af1v[3][2], af2[3][2];
    LOADW(wlane1, af0, 0);
    LOADW(wlane1, af1v, 1);
    __syncthreads();  // X0 staged
#pragma unroll 1
    for (int s = 0; s < 18; s += 3) {
      LOADW(wlane1, af2, s + 2);       // 2-ahead: lands after 2 MFMA phases
      COMP1(af0, s);
      if (s + 3 < 18) LOADW(wlane1, af0, s + 3);
      COMP1(af1v, s + 1);
      if (s + 4 < 18) LOADW(wlane1, af1v, s + 4);
      COMP1(af2, s + 2);
    }
  }

  // ---- epilogue1: bias+ReLU, LN stats (rows 0..65 meaningful) ----
#pragma unroll
  for (int fn = 0; fn < 3; ++fn) {
    const int nb = wid * 48 + fn * 16 + q * 4;
    float c0 = b1[nb], c1 = b1[nb + 1], c2 = b1[nb + 2], c3 = b1[nb + 3];
#pragma unroll
    for (int fm = 0; fm < 5; ++fm) {
      acc1[fn][fm][0] = fmaxf(acc1[fn][fm][0] + c0, 0.f);
      acc1[fn][fm][1] = fmaxf(acc1[fn][fm][1] + c1, 0.f);
      acc1[fn][fm][2] = fmaxf(acc1[fn][fm][2] + c2, 0.f);
      acc1[fn][fm][3] = fmaxf(acc1[fn][fm][3] + c3, 0.f);
    }
  }
#pragma unroll
  for (int fm = 0; fm < 5; ++fm) {
    float s = 0.f, s2 = 0.f;
#pragma unroll
    for (int fn = 0; fn < 3; ++fn)
#pragma unroll
      for (int j = 0; j < 4; ++j) {
        float v = acc1[fn][fm][j];
        s += v; s2 += v * v;
      }
    s += __shfl_xor(s, 16); s += __shfl_xor(s, 32);
    s2 += __shfl_xor(s2, 16); s2 += __shfl_xor(s2, 32);
    if (l < 16) { red[wid][fm * 16 + r16][0] = s; red[wid][fm * 16 + r16][1] = s2; }
  }
  __syncthreads();   // also guarantees all waves done reading X0
  if (tid < 66) {
    float S = 0.f, S2 = 0.f;
#pragma unroll
    for (int w = 0; w < 8; ++w) { S += red[w][tid][0]; S2 += red[w][tid][1]; }
    float mu = S / F_;
    stats[tid][0] = mu;
    stats[tid][1] = rsqrtf(S2 / F_ - mu * mu + 1e-5f);
  }
  __syncthreads();

  // ---- LN1 -> ldsX (swizzled bf16). Edge rows excluded (zeroed below). ----
  const int mlo = (t0 == 0) ? 1 : 0;
  const int mhi = (t0 == T_ - 64) ? 65 : 66;
#pragma unroll
  for (int fn = 0; fn < 3; ++fn) {
    const int nb = wid * 48 + fn * 16 + q * 4;
    float g0 = g1[nb], gg1 = g1[nb + 1], g2v = g1[nb + 2], g3 = g1[nb + 3];
    float e0 = be1[nb], e1 = be1[nb + 1], e2 = be1[nb + 2], e3 = be1[nb + 3];
#pragma unroll
    for (int fm = 0; fm < 5; ++fm) {
      const int m = fm * 16 + r16;
      if (m >= mlo && m < mhi) {
        const float mu = stats[m][0], rs = stats[m][1];
        uint32_t p0 = pack2((acc1[fn][fm][0] - mu) * rs * g0 + e0,
                            (acc1[fn][fm][1] - mu) * rs * gg1 + e1);
        uint32_t p1 = pack2((acc1[fn][fm][2] - mu) * rs * g2v + e2,
                            (acc1[fn][fm][3] - mu) * rs * g3 + e3);
        *(uint2*)(ldsX + m * 768 + (((nb >> 3) ^ (m & 7)) << 4) +
                  ((q & 1) << 3)) = make_uint2(p0, p1);
      }
    }
  }
  // conv2's zero padding at sequence edges (sole writer of these rows)
  if (t0 == 0 && tid < 48)
    *(uint4*)(ldsX + tid * 16) = make_uint4(0, 0, 0, 0);
  if (t0 == T_ - 64 && tid < 48)
    *(uint4*)(ldsX + 65 * 768 + tid * 16) = make_uint4(0, 0, 0, 0);

  // ================= GEMM2: 4 m-frags (reads ldsX rows 0..65) ==============
  f32x4 acc2[3][4];
#pragma unroll
  for (int fn = 0; fn < 3; ++fn)
#pragma unroll
    for (int fm = 0; fm < 4; ++fm) acc2[fn][fm] = (f32x4){0.f, 0.f, 0.f, 0.f};

  auto COMP2 = [&](bf16x8 (&af)[3][2], int s) {
    const int kk = s / 6, c128 = (s % 6) * 128;
#pragma unroll
    for (int ks = 0; ks < 2; ++ks) {
      bf16x8 bx[4];
#pragma unroll
      for (int fm = 0; fm < 4; ++fm) {
        int rl = fm * 16 + r16 + kk;
        bx[fm] = *(const bf16x8*)(ldsX + rl * 768 + c128 +
                                  (((ks * 4 + q) ^ (rl & 7)) << 4));
      }
#pragma unroll
      for (int fn = 0; fn < 3; ++fn)
#pragma unroll
        for (int fm = 0; fm < 4; ++fm)
          acc2[fn][fm] = __builtin_amdgcn_mfma_f32_16x16x32_bf16(
              af[fn][ks], bx[fm], acc2[fn][fm], 0, 0, 0);
    }
  };

  {
    bf16x8 af0[3][2], af1v[3][2], af2[3][2];
    LOADW(wlane2, af0, 0);   // issued before the barrier: hides L2 latency
    LOADW(wlane2, af1v, 1);
    __syncthreads();         // LN1 writes + pad zeros visible
#pragma unroll 1
    for (int s = 0; s < 18; s += 3) {
      LOADW(wlane2, af2, s + 2);
      COMP2(af0, s);
      if (s + 3 < 18) LOADW(wlane2, af0, s + 3);
      COMP2(af1v, s + 1);
      if (s + 4 < 18) LOADW(wlane2, af1v, s + 4);
      COMP2(af2, s + 2);
    }
  }

  // ---- epilogue2: bias+ReLU, LN, fused linear + mask -> dpo ----
#pragma unroll
  for (int fn = 0; fn < 3; ++fn) {
    const int nb = wid * 48 + fn * 16 + q * 4;
    float c0 = b2[nb], c1 = b2[nb + 1], c2 = b2[nb + 2], c3 = b2[nb + 3];
#pragma unroll
    for (int fm = 0; fm < 4; ++fm) {
      acc2[fn][fm][0] = fmaxf(acc2[fn][fm][0] + c0, 0.f);
      acc2[fn][fm][1] = fmaxf(acc2[fn][fm][1] + c1, 0.f);
      acc2[fn][fm][2] = fmaxf(acc2[fn][fm][2] + c2, 0.f);
      acc2[fn][fm][3] = fmaxf(acc2[fn][fm][3] + c3, 0.f);
    }
  }
  __syncthreads();  // red/stats reuse
#pragma unroll
  for (int fm = 0; fm < 4; ++fm) {
    float s = 0.f, s2 = 0.f;
#pragma unroll
    for (int fn = 0; fn < 3; ++fn)
#pragma unroll
      for (int j = 0; j < 4; ++j) {
        float v = acc2[fn][fm][j];
        s += v; s2 += v * v;
      }
    s += __shfl_xor(s, 16); s += __shfl_xor(s, 32);
    s2 += __shfl_xor(s2, 16); s2 += __shfl_xor(s2, 32);
    if (l < 16) { red[wid][fm * 16 + r16][0] = s; red[wid][fm * 16 + r16][1] = s2; }
  }
  __syncthreads();
  if (tid < 64) {
    float S = 0.f, S2 = 0.f;
#pragma unroll
    for (int w = 0; w < 8; ++w) { S += red[w][tid][0]; S2 += red[w][tid][1]; }
    float mu = S / F_;
    stats[tid][0] = mu;
    stats[tid][1] = rsqrtf(S2 / F_ - mu * mu + 1e-5f);
  }
  __syncthreads();

  float p[4] = {0.f, 0.f, 0.f, 0.f};
#pragma unroll
  for (int fn = 0; fn < 3; ++fn) {
    const int nb = wid * 48 + fn * 16 + q * 4;
    float g0 = g2[nb], gg1 = g2[nb + 1], g2v = g2[nb + 2], g3 = g2[nb + 3];
    float e0 = be2[nb], e1 = be2[nb + 1], e2 = be2[nb + 2], e3 = be2[nb + 3];
    float l0 = wl[nb], l1 = wl[nb + 1], l2 = wl[nb + 2], l3 = wl[nb + 3];
#pragma unroll
    for (int fm = 0; fm < 4; ++fm) {
      const int m = fm * 16 + r16;
      const float mu = stats[m][0], rs = stats[m][1];
      p[fm] += ((acc2[fn][fm][0] - mu) * rs * g0 + e0) * l0 +
               ((acc2[fn][fm][1] - mu) * rs * gg1 + e1) * l1 +
               ((acc2[fn][fm][2] - mu) * rs * g2v + e2) * l2 +
               ((acc2[fn][fm][3] - mu) * rs * g3 + e3) * l3;
    }
  }
  __syncthreads();  // red reuse
#pragma unroll
  for (int fm = 0; fm < 4; ++fm) {
    float s = p[fm];
    s += __shfl_xor(s, 16); s += __shfl_xor(s, 32);
    if (l < 16) red[wid][fm * 16 + r16][0] = s;
  }
  __syncthreads();
  if (tid < 64) {
    float S = 0.f;
#pragma unroll
    for (int w = 0; w < 8; ++w) S += red[w][tid][0];
    int t = t0 + tid;
    dpo[b * T_ + t] = (S + bl[0]) * mask[b * T_ + t];
  }
}

// ---------------------------------------------------------------------------
extern "C" void kernel_launch(void* const* d_in, const int* in_sizes, int n_in,
                              void* d_out, int out_size, void* d_ws,
                              size_t ws_size, hipStream_t stream) {
  const float* enc    = (const float*)d_in[0];
  const float* mask   = (const float*)d_in[1];
  const int*   target = (const int*)d_in[2];
  const float* w1    = (const float*)d_in[4];
  const float* b1    = (const float*)d_in[5];
  const float* g1    = (const float*)d_in[6];
  const float* beta1 = (const float*)d_in[7];
  const float* w2    = (const float*)d_in[8];
  const float* b2    = (const float*)d_in[9];
  const float* g2    = (const float*)d_in[10];
  const float* beta2 = (const float*)d_in[11];
  const float* wl    = (const float*)d_in[12];
  const float* bl    = (const float*)d_in[13];

  // Workspace (bf16): wt1 | wt2 (permuted)
  ushort_t* wt1 = (ushort_t*)d_ws;                    // [18][8][6][512]
  ushort_t* wt2 = wt1 + (size_t)F_ * KTOT;

  float* out0 = (float*)d_out;                        // [B,M,C]
  float* dec  = out0 + (size_t)B_ * M_ * C_;          // [B,M]
  float* dpo  = dec + (size_t)B_ * M_;                // [B,T]

  prep_expand_kernel<<<NWB + NEXB, 256, 0, stream>>>(
      target, w1, w2, enc, wt1, wt2, out0, dec);

  gemm12_kernel<<<256, 512, 0, stream>>>(
      enc, mask, wt1, wt2, b1, g1, beta1, b2, g2, beta2, wl, bl, dpo);
}